// Round 12
// baseline (193.400 us; speedup 1.0000x reference)
//
#include <hip/hip_runtime.h>
#include <stdint.h>

#define BB      8
#define HH      56
#define WWD     56
#define CCH     512
#define NHEADS  8
#define HD      64
#define NWIN    7
#define NREG    49
#define RSZ     64
#define TOPKK   4
#define PPI     (HH*WWD)        // 3136
#define NPIX    (BB*PPI)        // 25088
#define OC      (3*CCH)         // 1536
#define SCALE_F 0.04419417382415922f

typedef unsigned short u16;
typedef u16   u16x8 __attribute__((ext_vector_type(8)));
typedef u16   u16x4 __attribute__((ext_vector_type(4)));
typedef __bf16 b16x8 __attribute__((ext_vector_type(8)));
typedef float f32x4 __attribute__((ext_vector_type(4)));
typedef int   i32x4 __attribute__((ext_vector_type(4)));

__device__ __forceinline__ u16 f2b(float f){
    return __builtin_bit_cast(unsigned short, (__bf16)f);   // v_cvt_pk_bf16_f32, RNE
}
__device__ __forceinline__ float b2f(u16 h){
    return __builtin_bit_cast(float, (unsigned)h << 16);
}
__device__ __forceinline__ f32x4 MFMA(u16x8 a, u16x8 b, f32x4 c){
    return __builtin_amdgcn_mfma_f32_16x16x32_bf16(
        __builtin_bit_cast(b16x8, a), __builtin_bit_cast(b16x8, b), c, 0, 0, 0);
}
// XOR-swizzle term (u16-index units, 16B granular)
__device__ __forceinline__ int sw8(int row){ return ((row ^ (row >> 3)) & 7) << 3; }

// async global->LDS 16B
__device__ __forceinline__ void gld16(const void* g, void* l){
    auto gp = (const __attribute__((address_space(1))) unsigned int*)(unsigned long long)(g);
    auto lp = (__attribute__((address_space(3))) unsigned int*)(unsigned int)(unsigned long long)(l);
    __builtin_amdgcn_global_load_lds(gp, lp, 16, 0, 0);
}

// ---------------- fused: x fp32->bf16 convert + per-(region,row) channel sums ----------------
__global__ __launch_bounds__(256) void k_pool1(const float* __restrict__ x,
                                               u16* __restrict__ xb,
                                               float* __restrict__ xpp){
    __shared__ f32x4 ps[128];
    int blk = blockIdx.x;
    int br = blk >> 3, a = blk & 7;
    int b = br / NREG, reg = br % NREG;
    int rh = reg / NWIN, rw = reg % NWIN;
    size_t base_off = ((size_t)b*PPI + (rh*8 + a)*WWD + rw*8) * CCH;
    const f32x4* src = (const f32x4*)(x + base_off);
    u16* xbase = xb + base_off;
    int t = threadIdx.x;
    f32x4 s4 = (f32x4){0.f,0.f,0.f,0.f};
    #pragma unroll
    for (int i = 0; i < 4; i++){
        int c4 = t + 256*i;
        f32x4 v = src[c4];
        s4 += v;
        u16x4 o4; o4[0]=f2b(v[0]); o4[1]=f2b(v[1]); o4[2]=f2b(v[2]); o4[3]=f2b(v[3]);
        *(u16x4*)(xbase + c4*4) = o4;
    }
    if (t >= 128) ps[t-128] = s4;
    __syncthreads();
    if (t < 128){
        f32x4 r = ps[t];
        r += s4;
        *(f32x4*)(xpp + (size_t)blk*CCH + t*4) = r;
    }
}

// ---------------- pool stage 2: sum the 8 row-partials, /64. grid 784 ----------------
__global__ __launch_bounds__(256) void k_pool2(const float* __restrict__ xpp,
                                               float* __restrict__ xp){
    int i = blockIdx.x*256 + threadIdx.x;
    int br = i >> 9, c = i & 511;
    float s = 0.f;
    #pragma unroll
    for (int a = 0; a < 8; a++) s += xpp[((size_t)(br*8 + a))*CCH + c];
    xp[i] = s * (1.0f/64.0f);
}

// ---------------- both weight converts in one launch ----------------
__global__ __launch_bounds__(256) void k_conv_w(const float* __restrict__ w1,
                                                u16* __restrict__ d1,
                                                const float* __restrict__ w2,
                                                u16* __restrict__ d2){
    int i = blockIdx.x * 256 + threadIdx.x;
    const float* src = w1; u16* dst = d1;
    if (i >= OC*CCH/8){ i -= OC*CCH/8; src = w2; dst = d2; }
    const f32x4* s = (const f32x4*)src;
    f32x4 a = s[2*i], b = s[2*i+1];
    u16x8 o;
    o[0]=f2b(a[0]); o[1]=f2b(a[1]); o[2]=f2b(a[2]); o[3]=f2b(a[3]);
    o[4]=f2b(b[0]); o[5]=f2b(b[1]); o[6]=f2b(b[2]); o[7]=f2b(b[3]);
    *(u16x8*)(dst + 8*i) = o;
}

// ---------------- pooled q/k projection: fp32 split-K GEMM -> partials ----------------
#define QP_BM 64
#define QP_BN 64
#define QP_BK 32
#define QP_KS 4
__global__ __launch_bounds__(256) void k_qk_pool(const float* __restrict__ xp,
                                                 const float* __restrict__ qkv_w,
                                                 float* __restrict__ qkpp){
    __shared__ float Xs[QP_BK][QP_BM+4];
    __shared__ float Ws[QP_BK][QP_BN+4];
    int bx = blockIdx.x;                 // 7 mt x 16 nt x 4 kt = 448
    int kt = bx & 3, nt = (bx >> 2) & 15, mt = bx >> 6;
    int row0 = mt*QP_BM, o0 = nt*QP_BN, kbase = kt*(CCH/QP_KS);
    int t = threadIdx.x;
    int tx = t & 15, ty = t >> 4;
    float acc[4][4];
    #pragma unroll
    for (int i = 0; i < 4; i++)
        #pragma unroll
        for (int j = 0; j < 4; j++) acc[i][j] = 0.f;

    for (int ks = 0; ks < (CCH/QP_KS)/QP_BK; ks++){
        int k0 = kbase + ks*QP_BK;
        #pragma unroll
        for (int i = 0; i < 8; i++){
            int idx = t + 256*i;
            int row = idx >> 5, col = idx & 31;
            int gr = row0 + row;
            Xs[col][row] = (gr < BB*NREG) ? xp[(size_t)gr*CCH + k0 + col] : 0.f;
            Ws[col][row] = qkv_w[(size_t)(o0 + row)*CCH + k0 + col];
        }
        __syncthreads();
        #pragma unroll
        for (int kk = 0; kk < QP_BK; kk++){
            f32x4 a4 = *(const f32x4*)&Xs[kk][ty*4];
            f32x4 b4 = *(const f32x4*)&Ws[kk][tx*4];
            #pragma unroll
            for (int i = 0; i < 4; i++)
                #pragma unroll
                for (int j = 0; j < 4; j++)
                    acc[i][j] += a4[i] * b4[j];
        }
        __syncthreads();
    }
    float* dst = qkpp + (size_t)kt*(BB*NREG*1024);
    #pragma unroll
    for (int i = 0; i < 4; i++){
        int r = row0 + ty*4 + i;
        if (r >= BB*NREG) continue;
        #pragma unroll
        for (int j = 0; j < 4; j++){
            int o = o0 + tx*4 + j;
            dst[(size_t)r*1024 + o] = acc[i][j];
        }
    }
}

// ---------------- reduce split-K partials + bias. grid 1568 ----------------
__global__ __launch_bounds__(256) void k_qkp_red(const float* __restrict__ qkpp,
                                                 const float* __restrict__ qkv_b,
                                                 float* __restrict__ qkp){
    int i = blockIdx.x*256 + threadIdx.x;
    int o = i & 1023;
    float s = qkv_b[o];
    #pragma unroll
    for (int kt = 0; kt < QP_KS; kt++)
        s += qkpp[(size_t)kt*(BB*NREG*1024) + i];
    qkp[i] = s;
}

// ---------------- a_r scores + top-4 ----------------
__global__ __launch_bounds__(64) void k_route(const float* __restrict__ qkp,
                                              int* __restrict__ idx){
    int blk = blockIdx.x;
    int b = blk / NREG;
    int lane = threadIdx.x;
    __shared__ float sc[NREG];
    const float* qr = qkp + (size_t)blk*1024;
    float qv[8];
    #pragma unroll
    for (int i = 0; i < 8; i++) qv[i] = qr[lane + 64*i];
    for (int j = 0; j < NREG; j++){
        const float* kr = qkp + ((size_t)(b*NREG + j)*1024 + 512);
        float p = 0.f;
        #pragma unroll
        for (int i = 0; i < 8; i++) p += qv[i] * kr[lane + 64*i];
        #pragma unroll
        for (int msk = 32; msk >= 1; msk >>= 1) p += __shfl_xor(p, msk, 64);
        if (lane == 0) sc[j] = p;
    }
    __syncthreads();
    if (lane == 0){
        #pragma unroll
        for (int t = 0; t < TOPKK; t++){
            float best = -1e30f; int bj = 0;
            for (int j = 0; j < NREG; j++){
                if (sc[j] > best){ best = sc[j]; bj = j; }
            }
            idx[blk*TOPKK + t] = bj;
            sc[bj] = -1e30f;
        }
    }
}

// ---------------- QKV GEMM: 8-wave 128x128 tile, dbuf, single raw barrier per K-step ----------------
#define BM 128
#define BN 128
#define BK 64
__global__ __launch_bounds__(512) void k_gemm_qkv(const u16* __restrict__ xb,
                                                  const u16* __restrict__ wb,
                                                  const float* __restrict__ bias,
                                                  u16* __restrict__ q_s,
                                                  u16* __restrict__ k_s,
                                                  u16* __restrict__ v_s){
    __shared__ u16 As[2][BM*BK];
    __shared__ u16 Bs[2][BN*BK];
    int bx = (blockIdx.x & 7)*294 + (blockIdx.x >> 3);   // XCD-chunked (2352 = 8*294)
    int mt = bx / (OC/BN), nt = bx % (OC/BN);
    int pix0 = mt*BM, o0 = nt*BN;
    int t = threadIdx.x;
    int wid = t >> 6, lane = t & 63;
    int wm = wid >> 2, wn = wid & 3;          // wave tile 64 x 32
    int l15 = lane & 15, hi = lane >> 4;
    f32x4 acc[4][2];
    #pragma unroll
    for (int i = 0; i < 4; i++)
        #pragma unroll
        for (int j = 0; j < 2; j++) acc[i][j] = (f32x4){0.f,0.f,0.f,0.f};

    auto STAGE = [&](int sel, int ks){
        int K0 = ks*BK;
        #pragma unroll
        for (int i = 0; i < 2; i++){
            int off = t*16 + i*8192;
            int row = off >> 7;
            int cs  = ((off & 127) >> 1) ^ sw8(row);
            gld16(xb + (size_t)(pix0+row)*CCH + K0 + cs, (char*)As[sel] + off);
            gld16(wb + (size_t)(o0 +row)*CCH + K0 + cs, (char*)Bs[sel] + off);
        }
    };
    STAGE(0, 0);
    asm volatile("s_waitcnt vmcnt(0)" ::: "memory");
    asm volatile("s_barrier" ::: "memory");
    for (int ks = 0; ks < CCH/BK; ks++){
        int cur = ks & 1;
        if (ks < CCH/BK - 1) STAGE(cur ^ 1, ks + 1);   // prefetch flies under MFMA
        const u16* Ac = As[cur];
        const u16* Bc = Bs[cur];
        #pragma unroll
        for (int kk = 0; kk < 2; kk++){
            u16x8 af[4], bf[2];
            #pragma unroll
            for (int i = 0; i < 4; i++){
                int rowA = wm*64 + i*16 + l15;
                af[i] = *(const u16x8*)&Ac[rowA*BK + ((kk*32 + hi*8) ^ sw8(rowA))];
            }
            #pragma unroll
            for (int j = 0; j < 2; j++){
                int rowB = wn*32 + j*16 + l15;
                bf[j] = *(const u16x8*)&Bc[rowB*BK + ((kk*32 + hi*8) ^ sw8(rowB))];
            }
            #pragma unroll
            for (int i = 0; i < 4; i++)
                #pragma unroll
                for (int j = 0; j < 2; j++)
                    acc[i][j] = MFMA(af[i], bf[j], acc[i][j]);
        }
        asm volatile("s_waitcnt vmcnt(0)" ::: "memory");
        asm volatile("s_barrier" ::: "memory");
    }
    // epilogue: one div chain per i (4-pixel group shares b,h,reg)
    #pragma unroll
    for (int i = 0; i < 4; i++){
        int pix = pix0 + wm*64 + i*16 + 4*hi;        // %4 == 0
        int b  = pix / PPI;
        int pp = pix - b*PPI;
        int h  = pp / WWD, w2 = pp - h*WWD;
        int reg = (h >> 3)*NWIN + (w2 >> 3);
        int pr  = (h & 7)*8 + (w2 & 7);
        size_t base0 = ((size_t)(b*NHEADS)*NREG + reg)*RSZ + pr;
        #pragma unroll
        for (int j = 0; j < 2; j++){
            int o = o0 + wn*32 + j*16 + l15;
            int which = o >> 9;
            int c = o & 511;
            int m = c >> 6, d = c & 63;
            float bv = bias[o];
            u16* dst = (which == 0) ? q_s : (which == 1) ? k_s : v_s;
            size_t oi = (base0 + (size_t)m*(NREG*RSZ))*HD + d;
            #pragma unroll
            for (int r = 0; r < 4; r++)
                dst[oi + (size_t)r*HD] = f2b(acc[i][j][r] + bv);
        }
    }
}

// ---------------- fused attention + LEPE: 40KB LDS, 3 blocks/CU (unchanged, proven r11) ----------------
__global__ __launch_bounds__(256, 3) void k_attn(const u16* __restrict__ q_s,
                                              const u16* __restrict__ k_s,
                                              const u16* __restrict__ v_s,
                                              const int* __restrict__ idx,
                                              const float* __restrict__ lw,
                                              const float* __restrict__ lb,
                                              u16* __restrict__ yb){
    __shared__ __align__(16) char smem[32768 + 8192];
    u16*   Ks = (u16*)smem;
    u16*   Vt = (u16*)(smem + 32768);
    float* Wl = (float*)(smem + 14400);          // inside Ks region, after 100*72 u16 halo
    float* Bl = (float*)(smem + 14400 + 2304);
    int bid = (blockIdx.x & 7)*392 + (blockIdx.x >> 3);  // XCD-chunked
    int b  = bid / (NHEADS*NREG);
    int r2 = bid % (NHEADS*NREG);
    int m = r2 / NREG, qreg = r2 % NREG;
    int rh = qreg / NWIN, rw = qreg % NWIN;
    int t = threadIdx.x, wid = t >> 6, lane = t & 63;
    int l15 = lane & 15, hi = lane >> 4;

    size_t hb = (size_t)(b*NHEADS + m)*NREG;
    int i4[4];
    #pragma unroll
    for (int j = 0; j < 4; j++) i4[j] = idx[(b*NREG + qreg)*TOPKK + j];

    // lepe halo loads early (10x10 cells x 64 d, 8 d per chunk -> 800 chunks)
    u16x8 halo0 = (u16x8){0,0,0,0,0,0,0,0}, halo1 = halo0, halo2 = halo0, halo3 = halo0;
    #pragma unroll
    for (int i = 0; i < 4; i++){
        int c = t + 256*i;
        if (c < 800){
            int cell = c >> 3, part = c & 7;
            int hr = cell / 10, wc = cell % 10;
            int hh2 = rh*8 - 1 + hr, ww2 = rw*8 - 1 + wc;
            if (hh2 >= 0 && hh2 < HH && ww2 >= 0 && ww2 < WWD){
                int reg2 = (hh2 >> 3)*NWIN + (ww2 >> 3);
                int pr2  = (hh2 & 7)*8 + (ww2 & 7);
                u16x8 v8 = *(const u16x8*)&v_s[((hb + reg2)*RSZ + pr2)*HD + part*8];
                if (i == 0) halo0 = v8; else if (i == 1) halo1 = v8;
                else if (i == 2) halo2 = v8; else halo3 = v8;
            }
        }
    }

    // stage K via global_load_lds (swizzled through source column)
    #pragma unroll
    for (int i = 0; i < 8; i++){
        int off = t*16 + i*4096;
        int rsel = off >> 13;
        int row  = off >> 7;
        int cs   = ((off & 127) >> 1) ^ sw8(row);
        gld16(k_s + (hb + i4[rsel])*(RSZ*HD) + (size_t)(row & 63)*HD + cs,
              (char*)Ks + off);
    }
    const u16* qb = q_s + (hb + qreg)*(RSZ*HD);
    u16x8 aq[2];
    #pragma unroll
    for (int kk = 0; kk < 2; kk++)
        aq[kk] = *(const u16x8*)&qb[(wid*16 + l15)*HD + kk*32 + hi*8];
    __syncthreads();

    // QK^T
    f32x4 s[16];
    #pragma unroll
    for (int fn = 0; fn < 16; fn++) s[fn] = (f32x4){0.f,0.f,0.f,0.f};
    #pragma unroll
    for (int kk = 0; kk < 2; kk++)
        #pragma unroll
        for (int fn = 0; fn < 16; fn++){
            int rowK = fn*16 + l15;
            u16x8 bf = *(const u16x8*)&Ks[rowK*HD + ((kk*32 + hi*8) ^ sw8(rowK))];
            s[fn] = MFMA(aq[kk], bf, s[fn]);
        }
    // softmax: no max-sub (|s*scale| <= ~60 << 88 fp32-exp limit); inv deferred to post-PV
    const float K2 = SCALE_F * 1.4426950408889634f;  // scale * log2(e)
    float inv[4];
    #pragma unroll
    for (int rr = 0; rr < 4; rr++){
        float ss = 0.f;
        #pragma unroll
        for (int fn = 0; fn < 16; fn++){
            float e = exp2f(s[fn][rr] * K2);
            s[fn][rr] = e; ss += e;
        }
        #pragma unroll
        for (int msk = 1; msk < 16; msk <<= 1) ss += __shfl_xor(ss, msk, 64);
        inv[rr] = 1.0f / ss;
    }
    __syncthreads();
    // write unnormalized P (bf16) into Ks region as swizzled [64][256]
    #pragma unroll
    for (int fn = 0; fn < 16; fn++)
        #pragma unroll
        for (int rr = 0; rr < 4; rr++){
            int rowP = wid*16 + 4*hi + rr;
            Ks[rowP*256 + ((fn*16 + l15) ^ sw8(rowP))] = f2b(s[fn][rr]);
        }
    __syncthreads();

    // preload all 8 P fragments, then Ks region is free
    int rowP = wid*16 + l15;
    u16x8 pa8[8];
    #pragma unroll
    for (int ksx = 0; ksx < 8; ksx++)
        pa8[ksx] = *(const u16x8*)&Ks[rowP*256 + ((ksx*32 + hi*8) ^ sw8(rowP))];
    __syncthreads();               // all waves done reading P -> Ks reusable

    // halo + lepe weights -> Ks region
    #pragma unroll
    for (int i = 0; i < 4; i++){
        int c = t + 256*i;
        if (c < 800){
            int cell = c >> 3, part = c & 7;
            u16x8 v8 = (i == 0) ? halo0 : (i == 1) ? halo1 : (i == 2) ? halo2 : halo3;
            *(u16x8*)&Ks[cell*72 + part*8] = v8;
        }
    }
    #pragma unroll
    for (int i2 = t; i2 < 640; i2 += 256){
        if (i2 < 576) Wl[i2] = lw[m*576 + i2];
        else Bl[i2-576] = lb[m*64 + (i2-576)];
    }

    // PV: 4 phases, per-dblk V staging into 8KB Vt
    f32x4 o[4];
    #pragma unroll
    for (int j = 0; j < 4; j++) o[j] = (f32x4){0.f,0.f,0.f,0.f};
    #pragma unroll
    for (int j = 0; j < 4; j++){
        #pragma unroll
        for (int i2 = 0; i2 < 2; i2++){
            int c2 = t + 256*i2;
            int key = c2 >> 1, dhalf = c2 & 1;
            u16x8 v8 = *(const u16x8*)&v_s[(hb + i4[key >> 6])*(RSZ*HD)
                                           + (size_t)(key & 63)*HD + j*16 + dhalf*8];
            #pragma unroll
            for (int jj = 0; jj < 8; jj++){
                int row = dhalf*8 + jj;
                Vt[row*256 + (key ^ sw8(row))] = v8[jj];
            }
        }
        __syncthreads();
        #pragma unroll
        for (int ksx = 0; ksx < 8; ksx++){
            u16x8 vb = *(const u16x8*)&Vt[l15*256 + ((ksx*32 + hi*8) ^ sw8(l15))];
            o[j] = MFMA(pa8[ksx], vb, o[j]);
        }
        __syncthreads();
    }
    // deferred softmax normalization (lane-local: o row = 4*hi+rr matches inv[rr])
    #pragma unroll
    for (int j = 0; j < 4; j++)
        #pragma unroll
        for (int rr = 0; rr < 4; rr++) o[j][rr] *= inv[rr];

    // lepe + output, 6-col register window
    int a_row = wid*2 + (hi >> 1);
    int col0  = (hi & 1)*4;
    #pragma unroll
    for (int j = 0; j < 4; j++){
        int d = j*16 + l15;
        float w9[9];
        #pragma unroll
        for (int tap = 0; tap < 9; tap++) w9[tap] = Wl[d*9 + tap];
        float bias = Bl[d];
        float accL[4] = {bias, bias, bias, bias};
        #pragma unroll
        for (int kh = 0; kh < 3; kh++){
            float c6[6];
            #pragma unroll
            for (int ii = 0; ii < 6; ii++)
                c6[ii] = b2f(Ks[((a_row + kh)*10 + col0 + ii)*72 + d]);
            #pragma unroll
            for (int rr = 0; rr < 4; rr++)
                #pragma unroll
                for (int kw = 0; kw < 3; kw++)
                    accL[rr] += c6[rr + kw] * w9[kh*3 + kw];
        }
        #pragma unroll
        for (int rr = 0; rr < 4; rr++){
            float val = o[j][rr] + accL[rr];
            int col = col0 + rr;
            int h = rh*8 + a_row, w2c = rw*8 + col;
            yb[((size_t)b*PPI + h*WWD + w2c)*CCH + m*HD + d] = f2b(val);
        }
    }
}

// ---------------- output GEMM: 8-wave 128x128 tile, dbuf, single raw barrier per K-step ----------------
__global__ __launch_bounds__(512) void k_gemm_out(const u16* __restrict__ yb,
                                                  const u16* __restrict__ wb,
                                                  const float* __restrict__ bias,
                                                  float* __restrict__ out){
    __shared__ u16 As[2][BM*BK];
    __shared__ u16 Bs[2][BN*BK];
    int bx = (blockIdx.x & 7)*98 + (blockIdx.x >> 3);    // XCD-chunked (784 = 8*98)
    int mt = bx >> 2, nt = bx & 3;
    int pix0 = mt*BM, o0 = nt*BN;
    int t = threadIdx.x;
    int wid = t >> 6, lane = t & 63;
    int wm = wid >> 2, wn = wid & 3;          // wave tile 64 x 32
    int l15 = lane & 15, hi = lane >> 4;
    f32x4 acc[4][2];
    #pragma unroll
    for (int i = 0; i < 4; i++)
        #pragma unroll
        for (int j = 0; j < 2; j++) acc[i][j] = (f32x4){0.f,0.f,0.f,0.f};

    auto STAGE = [&](int sel, int ks){
        int K0 = ks*BK;
        #pragma unroll
        for (int i = 0; i < 2; i++){
            int off = t*16 + i*8192;
            int row = off >> 7;
            int cs  = ((off & 127) >> 1) ^ sw8(row);
            gld16(yb + (size_t)(pix0+row)*CCH + K0 + cs, (char*)As[sel] + off);
            gld16(wb + (size_t)(o0 +row)*CCH + K0 + cs, (char*)Bs[sel] + off);
        }
    };
    STAGE(0, 0);
    asm volatile("s_waitcnt vmcnt(0)" ::: "memory");
    asm volatile("s_barrier" ::: "memory");
    for (int ks = 0; ks < CCH/BK; ks++){
        int cur = ks & 1;
        if (ks < CCH/BK - 1) STAGE(cur ^ 1, ks + 1);
        const u16* Ac = As[cur];
        const u16* Bc = Bs[cur];
        #pragma unroll
        for (int kk = 0; kk < 2; kk++){
            u16x8 af[4], bf[2];
            #pragma unroll
            for (int i = 0; i < 4; i++){
                int rowA = wm*64 + i*16 + l15;
                af[i] = *(const u16x8*)&Ac[rowA*BK + ((kk*32 + hi*8) ^ sw8(rowA))];
            }
            #pragma unroll
            for (int j = 0; j < 2; j++){
                int rowB = wn*32 + j*16 + l15;
                bf[j] = *(const u16x8*)&Bc[rowB*BK + ((kk*32 + hi*8) ^ sw8(rowB))];
            }
            #pragma unroll
            for (int i = 0; i < 4; i++)
                #pragma unroll
                for (int j = 0; j < 2; j++)
                    acc[i][j] = MFMA(af[i], bf[j], acc[i][j]);
        }
        asm volatile("s_waitcnt vmcnt(0)" ::: "memory");
        asm volatile("s_barrier" ::: "memory");
    }
    #pragma unroll
    for (int i = 0; i < 4; i++){
        #pragma unroll
        for (int j = 0; j < 2; j++){
            int o = o0 + wn*32 + j*16 + l15;
            float bv = bias[o];
            #pragma unroll
            for (int r = 0; r < 4; r++){
                int pix = pix0 + wm*64 + i*16 + 4*hi + r;
                out[(size_t)pix*CCH + o] = acc[i][j][r] + bv;
            }
        }
    }
}

// ---------------- launch ----------------
extern "C" void kernel_launch(void* const* d_in, const int* in_sizes, int n_in,
                              void* d_out, int out_size, void* d_ws, size_t ws_size,
                              hipStream_t stream){
    const float* x      = (const float*)d_in[0];
    const float* qkv_w  = (const float*)d_in[1];
    const float* qkv_b  = (const float*)d_in[2];
    const float* lepe_w = (const float*)d_in[3];
    const float* lepe_b = (const float*)d_in[4];
    const float* out_w  = (const float*)d_in[5];
    const float* out_b  = (const float*)d_in[6];

    char* w = (char*)d_ws;
    u16*   xb   = (u16*)(w + 0);
    u16*   wqkv = (u16*)(w + 25690112);
    u16*   wout = (u16*)(w + 27262976);
    u16*   q_s  = (u16*)(w + 27787264);
    u16*   k_s  = (u16*)(w + 53477376);
    u16*   v_s  = (u16*)(w + 79167488);
    float* xp   = (float*)(w + 104857600);
    float* qkp  = (float*)(w + 105660416);
    int*   idx  = (int*)(w + 107266048);
    u16*   yb   = (u16*)(w + 107272320);
    float* xpp  = (float*)(w + 132962432);
    float* qkpp = (float*)(w + 139384960);

    k_pool1<<<dim3(BB*NREG*8), dim3(256), 0, stream>>>(x, xb, xpp);
    k_pool2<<<dim3(BB*NREG*2), dim3(256), 0, stream>>>(xpp, xp);
    k_conv_w<<<dim3(512), dim3(256), 0, stream>>>(qkv_w, wqkv, out_w, wout);
    k_qk_pool<<<dim3(448), dim3(256), 0, stream>>>(xp, qkv_w, qkpp);
    k_qkp_red<<<dim3(BB*NREG*4), dim3(256), 0, stream>>>(qkpp, qkv_b, qkp);
    k_route<<<dim3(BB*NREG), dim3(64), 0, stream>>>(qkp, idx);
    k_gemm_qkv<<<dim3((NPIX/BM)*(OC/BN)), dim3(512), 0, stream>>>(xb, wqkv, qkv_b, q_s, k_s, v_s);
    k_attn<<<dim3(BB*NHEADS*NREG), dim3(256), 0, stream>>>(q_s, k_s, v_s, idx, lepe_w, lepe_b, yb);
    k_gemm_out<<<dim3((NPIX/BM)*(CCH/BN)), dim3(512), 0, stream>>>(yb, wout, out_b, (float*)d_out);
}

// Round 13
// 188.894 us; speedup vs baseline: 1.0239x; 1.0239x over previous
//
#include <hip/hip_runtime.h>
#include <stdint.h>

#define BB      8
#define HH      56
#define WWD     56
#define CCH     512
#define NHEADS  8
#define HD      64
#define NWIN    7
#define NREG    49
#define RSZ     64
#define TOPKK   4
#define PPI     (HH*WWD)        // 3136
#define NPIX    (BB*PPI)        // 25088
#define OC      (3*CCH)         // 1536
#define SCALE_F 0.04419417382415922f

typedef unsigned short u16;
typedef u16   u16x8 __attribute__((ext_vector_type(8)));
typedef u16   u16x4 __attribute__((ext_vector_type(4)));
typedef __bf16 b16x8 __attribute__((ext_vector_type(8)));
typedef float f32x4 __attribute__((ext_vector_type(4)));
typedef int   i32x4 __attribute__((ext_vector_type(4)));

__device__ __forceinline__ u16 f2b(float f){
    return __builtin_bit_cast(unsigned short, (__bf16)f);   // v_cvt_pk_bf16_f32, RNE
}
__device__ __forceinline__ float b2f(u16 h){
    return __builtin_bit_cast(float, (unsigned)h << 16);
}
__device__ __forceinline__ f32x4 MFMA(u16x8 a, u16x8 b, f32x4 c){
    return __builtin_amdgcn_mfma_f32_16x16x32_bf16(
        __builtin_bit_cast(b16x8, a), __builtin_bit_cast(b16x8, b), c, 0, 0, 0);
}
// XOR-swizzle term (u16-index units, 16B granular)
__device__ __forceinline__ int sw8(int row){ return ((row ^ (row >> 3)) & 7) << 3; }

// async global->LDS 16B
__device__ __forceinline__ void gld16(const void* g, void* l){
    auto gp = (const __attribute__((address_space(1))) unsigned int*)(unsigned long long)(g);
    auto lp = (__attribute__((address_space(3))) unsigned int*)(unsigned int)(unsigned long long)(l);
    __builtin_amdgcn_global_load_lds(gp, lp, 16, 0, 0);
}

// ---------------- fused: x fp32->bf16 convert + per-(region,row) channel sums ----------------
__global__ __launch_bounds__(256) void k_pool1(const float* __restrict__ x,
                                               u16* __restrict__ xb,
                                               float* __restrict__ xpp){
    __shared__ f32x4 ps[128];
    int blk = blockIdx.x;
    int br = blk >> 3, a = blk & 7;
    int b = br / NREG, reg = br % NREG;
    int rh = reg / NWIN, rw = reg % NWIN;
    size_t base_off = ((size_t)b*PPI + (rh*8 + a)*WWD + rw*8) * CCH;
    const f32x4* src = (const f32x4*)(x + base_off);
    u16* xbase = xb + base_off;
    int t = threadIdx.x;
    f32x4 s4 = (f32x4){0.f,0.f,0.f,0.f};
    #pragma unroll
    for (int i = 0; i < 4; i++){
        int c4 = t + 256*i;
        f32x4 v = src[c4];
        s4 += v;
        u16x4 o4; o4[0]=f2b(v[0]); o4[1]=f2b(v[1]); o4[2]=f2b(v[2]); o4[3]=f2b(v[3]);
        *(u16x4*)(xbase + c4*4) = o4;
    }
    if (t >= 128) ps[t-128] = s4;
    __syncthreads();
    if (t < 128){
        f32x4 r = ps[t];
        r += s4;
        *(f32x4*)(xpp + (size_t)blk*CCH + t*4) = r;
    }
}

// ---------------- pool stage 2: sum the 8 row-partials, /64. grid 784 ----------------
__global__ __launch_bounds__(256) void k_pool2(const float* __restrict__ xpp,
                                               float* __restrict__ xp){
    int i = blockIdx.x*256 + threadIdx.x;
    int br = i >> 9, c = i & 511;
    float s = 0.f;
    #pragma unroll
    for (int a = 0; a < 8; a++) s += xpp[((size_t)(br*8 + a))*CCH + c];
    xp[i] = s * (1.0f/64.0f);
}

// ---------------- both weight converts in one launch ----------------
__global__ __launch_bounds__(256) void k_conv_w(const float* __restrict__ w1,
                                                u16* __restrict__ d1,
                                                const float* __restrict__ w2,
                                                u16* __restrict__ d2){
    int i = blockIdx.x * 256 + threadIdx.x;
    const float* src = w1; u16* dst = d1;
    if (i >= OC*CCH/8){ i -= OC*CCH/8; src = w2; dst = d2; }
    const f32x4* s = (const f32x4*)src;
    f32x4 a = s[2*i], b = s[2*i+1];
    u16x8 o;
    o[0]=f2b(a[0]); o[1]=f2b(a[1]); o[2]=f2b(a[2]); o[3]=f2b(a[3]);
    o[4]=f2b(b[0]); o[5]=f2b(b[1]); o[6]=f2b(b[2]); o[7]=f2b(b[3]);
    *(u16x8*)(dst + 8*i) = o;
}

// ---------------- pooled q/k projection: fp32 split-K GEMM -> partials ----------------
#define QP_BM 64
#define QP_BN 64
#define QP_BK 32
#define QP_KS 4
__global__ __launch_bounds__(256) void k_qk_pool(const float* __restrict__ xp,
                                                 const float* __restrict__ qkv_w,
                                                 float* __restrict__ qkpp){
    __shared__ float Xs[QP_BK][QP_BM+4];
    __shared__ float Ws[QP_BK][QP_BN+4];
    int bx = blockIdx.x;                 // 7 mt x 16 nt x 4 kt = 448
    int kt = bx & 3, nt = (bx >> 2) & 15, mt = bx >> 6;
    int row0 = mt*QP_BM, o0 = nt*QP_BN, kbase = kt*(CCH/QP_KS);
    int t = threadIdx.x;
    int tx = t & 15, ty = t >> 4;
    float acc[4][4];
    #pragma unroll
    for (int i = 0; i < 4; i++)
        #pragma unroll
        for (int j = 0; j < 4; j++) acc[i][j] = 0.f;

    for (int ks = 0; ks < (CCH/QP_KS)/QP_BK; ks++){
        int k0 = kbase + ks*QP_BK;
        #pragma unroll
        for (int i = 0; i < 8; i++){
            int idx = t + 256*i;
            int row = idx >> 5, col = idx & 31;
            int gr = row0 + row;
            Xs[col][row] = (gr < BB*NREG) ? xp[(size_t)gr*CCH + k0 + col] : 0.f;
            Ws[col][row] = qkv_w[(size_t)(o0 + row)*CCH + k0 + col];
        }
        __syncthreads();
        #pragma unroll
        for (int kk = 0; kk < QP_BK; kk++){
            f32x4 a4 = *(const f32x4*)&Xs[kk][ty*4];
            f32x4 b4 = *(const f32x4*)&Ws[kk][tx*4];
            #pragma unroll
            for (int i = 0; i < 4; i++)
                #pragma unroll
                for (int j = 0; j < 4; j++)
                    acc[i][j] += a4[i] * b4[j];
        }
        __syncthreads();
    }
    float* dst = qkpp + (size_t)kt*(BB*NREG*1024);
    #pragma unroll
    for (int i = 0; i < 4; i++){
        int r = row0 + ty*4 + i;
        if (r >= BB*NREG) continue;
        #pragma unroll
        for (int j = 0; j < 4; j++){
            int o = o0 + tx*4 + j;
            dst[(size_t)r*1024 + o] = acc[i][j];
        }
    }
}

// ---------------- reduce split-K partials + bias. grid 1568 ----------------
__global__ __launch_bounds__(256) void k_qkp_red(const float* __restrict__ qkpp,
                                                 const float* __restrict__ qkv_b,
                                                 float* __restrict__ qkp){
    int i = blockIdx.x*256 + threadIdx.x;
    int o = i & 1023;
    float s = qkv_b[o];
    #pragma unroll
    for (int kt = 0; kt < QP_KS; kt++)
        s += qkpp[(size_t)kt*(BB*NREG*1024) + i];
    qkp[i] = s;
}

// ---------------- a_r scores + top-4 ----------------
__global__ __launch_bounds__(64) void k_route(const float* __restrict__ qkp,
                                              int* __restrict__ idx){
    int blk = blockIdx.x;
    int b = blk / NREG;
    int lane = threadIdx.x;
    __shared__ float sc[NREG];
    const float* qr = qkp + (size_t)blk*1024;
    float qv[8];
    #pragma unroll
    for (int i = 0; i < 8; i++) qv[i] = qr[lane + 64*i];
    for (int j = 0; j < NREG; j++){
        const float* kr = qkp + ((size_t)(b*NREG + j)*1024 + 512);
        float p = 0.f;
        #pragma unroll
        for (int i = 0; i < 8; i++) p += qv[i] * kr[lane + 64*i];
        #pragma unroll
        for (int msk = 32; msk >= 1; msk >>= 1) p += __shfl_xor(p, msk, 64);
        if (lane == 0) sc[j] = p;
    }
    __syncthreads();
    if (lane == 0){
        #pragma unroll
        for (int t = 0; t < TOPKK; t++){
            float best = -1e30f; int bj = 0;
            for (int j = 0; j < NREG; j++){
                if (sc[j] > best){ best = sc[j]; bj = j; }
            }
            idx[blk*TOPKK + t] = bj;
            sc[bj] = -1e30f;
        }
    }
}

// ---------------- QKV GEMM: r11-proven 4-wave dbuf, single raw barrier per K-step ----------------
#define BM 128
#define BN 128
#define BK 64
__global__ __launch_bounds__(256) void k_gemm_qkv(const u16* __restrict__ xb,
                                                  const u16* __restrict__ wb,
                                                  const float* __restrict__ bias,
                                                  u16* __restrict__ q_s,
                                                  u16* __restrict__ k_s,
                                                  u16* __restrict__ v_s){
    __shared__ u16 As[2][BM*BK];
    __shared__ u16 Bs[2][BN*BK];
    int bx = (blockIdx.x & 7)*294 + (blockIdx.x >> 3);   // XCD-chunked
    int mt = bx / (OC/BN), nt = bx % (OC/BN);
    int pix0 = mt*BM, o0 = nt*BN;
    int t = threadIdx.x;
    int wid = t >> 6, lane = t & 63;
    int wm = wid >> 1, wn = wid & 1;
    int l15 = lane & 15, hi = lane >> 4;
    f32x4 acc[4][4];
    #pragma unroll
    for (int i = 0; i < 4; i++)
        #pragma unroll
        for (int j = 0; j < 4; j++) acc[i][j] = (f32x4){0.f,0.f,0.f,0.f};

    auto STAGE = [&](int sel, int ks){
        int K0 = ks*BK;
        #pragma unroll
        for (int i = 0; i < 4; i++){
            int off = t*16 + i*4096;
            int row = off >> 7;
            int cs  = ((off & 127) >> 1) ^ sw8(row);
            gld16(xb + (size_t)(pix0+row)*CCH + K0 + cs, (char*)As[sel] + off);
            gld16(wb + (size_t)(o0 +row)*CCH + K0 + cs, (char*)Bs[sel] + off);
        }
    };
    STAGE(0, 0);
    asm volatile("s_waitcnt vmcnt(0)" ::: "memory");
    asm volatile("s_barrier" ::: "memory");
    for (int ks = 0; ks < CCH/BK; ks++){
        int cur = ks & 1;
        if (ks < CCH/BK - 1) STAGE(cur ^ 1, ks + 1);
        const u16* Ac = As[cur];
        const u16* Bc = Bs[cur];
        #pragma unroll
        for (int kk = 0; kk < 2; kk++){
            u16x8 af[4], bf[4];
            #pragma unroll
            for (int i = 0; i < 4; i++){
                int rowA = wm*64 + i*16 + l15;
                af[i] = *(const u16x8*)&Ac[rowA*BK + ((kk*32 + hi*8) ^ sw8(rowA))];
            }
            #pragma unroll
            for (int j = 0; j < 4; j++){
                int rowB = wn*64 + j*16 + l15;
                bf[j] = *(const u16x8*)&Bc[rowB*BK + ((kk*32 + hi*8) ^ sw8(rowB))];
            }
            #pragma unroll
            for (int i = 0; i < 4; i++)
                #pragma unroll
                for (int j = 0; j < 4; j++)
                    acc[i][j] = MFMA(af[i], bf[j], acc[i][j]);
        }
        asm volatile("s_waitcnt vmcnt(0)" ::: "memory");
        asm volatile("s_barrier" ::: "memory");
    }
    #pragma unroll
    for (int i = 0; i < 4; i++){
        int pix = pix0 + wm*64 + i*16 + 4*hi;
        int b  = pix / PPI;
        int pp = pix - b*PPI;
        int h  = pp / WWD, w2 = pp - h*WWD;
        int reg = (h >> 3)*NWIN + (w2 >> 3);
        int pr  = (h & 7)*8 + (w2 & 7);
        size_t base0 = ((size_t)(b*NHEADS)*NREG + reg)*RSZ + pr;
        #pragma unroll
        for (int j = 0; j < 4; j++){
            int o = o0 + wn*64 + j*16 + l15;
            int which = o >> 9;
            int c = o & 511;
            int m = c >> 6, d = c & 63;
            float bv = bias[o];
            u16* dst = (which == 0) ? q_s : (which == 1) ? k_s : v_s;
            size_t oi = (base0 + (size_t)m*(NREG*RSZ))*HD + d;
            #pragma unroll
            for (int r = 0; r < 4; r++)
                dst[oi + (size_t)r*HD] = f2b(acc[i][j][r] + bv);
        }
    }
}

// ---------------- fused attention + LEPE: 40KB LDS, 3 blocks/CU, pipelined PV loads ----------------
__global__ __launch_bounds__(256, 3) void k_attn(const u16* __restrict__ q_s,
                                              const u16* __restrict__ k_s,
                                              const u16* __restrict__ v_s,
                                              const int* __restrict__ idx,
                                              const float* __restrict__ lw,
                                              const float* __restrict__ lb,
                                              u16* __restrict__ yb){
    __shared__ __align__(16) char smem[32768 + 8192];
    u16*   Ks = (u16*)smem;
    u16*   Vt = (u16*)(smem + 32768);
    float* Wl = (float*)(smem + 14400);          // inside Ks region, after 100*72 u16 halo
    float* Bl = (float*)(smem + 14400 + 2304);
    int bid = (blockIdx.x & 7)*392 + (blockIdx.x >> 3);  // XCD-chunked
    int b  = bid / (NHEADS*NREG);
    int r2 = bid % (NHEADS*NREG);
    int m = r2 / NREG, qreg = r2 % NREG;
    int rh = qreg / NWIN, rw = qreg % NWIN;
    int t = threadIdx.x, wid = t >> 6, lane = t & 63;
    int l15 = lane & 15, hi = lane >> 4;

    size_t hb = (size_t)(b*NHEADS + m)*NREG;
    int i4[4];
    #pragma unroll
    for (int j = 0; j < 4; j++) i4[j] = idx[(b*NREG + qreg)*TOPKK + j];

    // lepe halo loads early (10x10 cells x 64 d, 8 d per chunk -> 800 chunks)
    u16x8 halo0 = (u16x8){0,0,0,0,0,0,0,0}, halo1 = halo0, halo2 = halo0, halo3 = halo0;
    #pragma unroll
    for (int i = 0; i < 4; i++){
        int c = t + 256*i;
        if (c < 800){
            int cell = c >> 3, part = c & 7;
            int hr = cell / 10, wc = cell % 10;
            int hh2 = rh*8 - 1 + hr, ww2 = rw*8 - 1 + wc;
            if (hh2 >= 0 && hh2 < HH && ww2 >= 0 && ww2 < WWD){
                int reg2 = (hh2 >> 3)*NWIN + (ww2 >> 3);
                int pr2  = (hh2 & 7)*8 + (ww2 & 7);
                u16x8 v8 = *(const u16x8*)&v_s[((hb + reg2)*RSZ + pr2)*HD + part*8];
                if (i == 0) halo0 = v8; else if (i == 1) halo1 = v8;
                else if (i == 2) halo2 = v8; else halo3 = v8;
            }
        }
    }

    // stage K via global_load_lds (swizzled through source column)
    #pragma unroll
    for (int i = 0; i < 8; i++){
        int off = t*16 + i*4096;
        int rsel = off >> 13;
        int row  = off >> 7;
        int cs   = ((off & 127) >> 1) ^ sw8(row);
        gld16(k_s + (hb + i4[rsel])*(RSZ*HD) + (size_t)(row & 63)*HD + cs,
              (char*)Ks + off);
    }
    const u16* qb = q_s + (hb + qreg)*(RSZ*HD);
    u16x8 aq[2];
    #pragma unroll
    for (int kk = 0; kk < 2; kk++)
        aq[kk] = *(const u16x8*)&qb[(wid*16 + l15)*HD + kk*32 + hi*8];
    __syncthreads();

    // QK^T
    f32x4 s[16];
    #pragma unroll
    for (int fn = 0; fn < 16; fn++) s[fn] = (f32x4){0.f,0.f,0.f,0.f};
    #pragma unroll
    for (int kk = 0; kk < 2; kk++)
        #pragma unroll
        for (int fn = 0; fn < 16; fn++){
            int rowK = fn*16 + l15;
            u16x8 bf = *(const u16x8*)&Ks[rowK*HD + ((kk*32 + hi*8) ^ sw8(rowK))];
            s[fn] = MFMA(aq[kk], bf, s[fn]);
        }
    // softmax: no max-sub (|s*scale| <= ~60 << 88 fp32-exp limit); inv deferred to post-PV
    const float K2 = SCALE_F * 1.4426950408889634f;  // scale * log2(e)
    float inv[4];
    #pragma unroll
    for (int rr = 0; rr < 4; rr++){
        float ss = 0.f;
        #pragma unroll
        for (int fn = 0; fn < 16; fn++){
            float e = exp2f(s[fn][rr] * K2);
            s[fn][rr] = e; ss += e;
        }
        #pragma unroll
        for (int msk = 1; msk < 16; msk <<= 1) ss += __shfl_xor(ss, msk, 64);
        inv[rr] = 1.0f / ss;
    }
    __syncthreads();
    // write unnormalized P (bf16) into Ks region as swizzled [64][256]
    #pragma unroll
    for (int fn = 0; fn < 16; fn++)
        #pragma unroll
        for (int rr = 0; rr < 4; rr++){
            int rowP = wid*16 + 4*hi + rr;
            Ks[rowP*256 + ((fn*16 + l15) ^ sw8(rowP))] = f2b(s[fn][rr]);
        }
    __syncthreads();

    // preload all 8 P fragments, then Ks region is free
    int rowP = wid*16 + l15;
    u16x8 pa8[8];
    #pragma unroll
    for (int ksx = 0; ksx < 8; ksx++)
        pa8[ksx] = *(const u16x8*)&Ks[rowP*256 + ((ksx*32 + hi*8) ^ sw8(rowP))];
    __syncthreads();               // all waves done reading P -> Ks reusable

    // issue PV phase-0 global loads NOW (consumed in first scatter; overlap halo/Wl staging)
    int keyA = t >> 1,        dhA = t & 1;          // c2 = t
    int keyB = (t+256) >> 1,  dhB = (t+256) & 1;    // c2 = t+256
    const u16* vbaseA = v_s + (hb + i4[keyA >> 6])*(RSZ*HD) + (size_t)(keyA & 63)*HD;
    const u16* vbaseB = v_s + (hb + i4[keyB >> 6])*(RSZ*HD) + (size_t)(keyB & 63)*HD;
    u16x8 ga = *(const u16x8*)&vbaseA[0*16 + dhA*8];
    u16x8 gb = *(const u16x8*)&vbaseB[0*16 + dhB*8];

    // halo + lepe weights -> Ks region
    #pragma unroll
    for (int i = 0; i < 4; i++){
        int c = t + 256*i;
        if (c < 800){
            int cell = c >> 3, part = c & 7;
            u16x8 v8 = (i == 0) ? halo0 : (i == 1) ? halo1 : (i == 2) ? halo2 : halo3;
            *(u16x8*)&Ks[cell*72 + part*8] = v8;
        }
    }
    #pragma unroll
    for (int i2 = t; i2 < 640; i2 += 256){
        if (i2 < 576) Wl[i2] = lw[m*576 + i2];
        else Bl[i2-576] = lb[m*64 + (i2-576)];
    }

    // PV: 4 phases; phase j+1's global loads issue before phase j's MFMA (latency hidden)
    f32x4 o[4];
    #pragma unroll
    for (int j = 0; j < 4; j++) o[j] = (f32x4){0.f,0.f,0.f,0.f};
    #pragma unroll
    for (int j = 0; j < 4; j++){
        // scatter current phase's registers into Vt (swizzled transpose)
        #pragma unroll
        for (int jj = 0; jj < 8; jj++){
            int rowA = dhA*8 + jj;
            Vt[rowA*256 + (keyA ^ sw8(rowA))] = ga[jj];
            int rowB = dhB*8 + jj;
            Vt[rowB*256 + (keyB ^ sw8(rowB))] = gb[jj];
        }
        __syncthreads();                           // Vt writes visible
        u16x8 na, nb;
        if (j < 3){                                // issue next phase's loads early
            na = *(const u16x8*)&vbaseA[(j+1)*16 + dhA*8];
            nb = *(const u16x8*)&vbaseB[(j+1)*16 + dhB*8];
        }
        #pragma unroll
        for (int ksx = 0; ksx < 8; ksx++){
            u16x8 vb = *(const u16x8*)&Vt[l15*256 + ((ksx*32 + hi*8) ^ sw8(l15))];
            o[j] = MFMA(pa8[ksx], vb, o[j]);
        }
        __syncthreads();                           // PV reads done before next scatter
        if (j < 3){ ga = na; gb = nb; }
    }
    // deferred softmax normalization (lane-local: o row = 4*hi+rr matches inv[rr])
    #pragma unroll
    for (int j = 0; j < 4; j++)
        #pragma unroll
        for (int rr = 0; rr < 4; rr++) o[j][rr] *= inv[rr];

    // lepe + output, 6-col register window
    int a_row = wid*2 + (hi >> 1);
    int col0  = (hi & 1)*4;
    #pragma unroll
    for (int j = 0; j < 4; j++){
        int d = j*16 + l15;
        float w9[9];
        #pragma unroll
        for (int tap = 0; tap < 9; tap++) w9[tap] = Wl[d*9 + tap];
        float bias = Bl[d];
        float accL[4] = {bias, bias, bias, bias};
        #pragma unroll
        for (int kh = 0; kh < 3; kh++){
            float c6[6];
            #pragma unroll
            for (int ii = 0; ii < 6; ii++)
                c6[ii] = b2f(Ks[((a_row + kh)*10 + col0 + ii)*72 + d]);
            #pragma unroll
            for (int rr = 0; rr < 4; rr++)
                #pragma unroll
                for (int kw = 0; kw < 3; kw++)
                    accL[rr] += c6[rr + kw] * w9[kh*3 + kw];
        }
        #pragma unroll
        for (int rr = 0; rr < 4; rr++){
            float val = o[j][rr] + accL[rr];
            int col = col0 + rr;
            int h = rh*8 + a_row, w2c = rw*8 + col;
            yb[((size_t)b*PPI + h*WWD + w2c)*CCH + m*HD + d] = f2b(val);
        }
    }
}

// ---------------- output GEMM: r11-proven 4-wave dbuf, single raw barrier per K-step ----------------
__global__ __launch_bounds__(256) void k_gemm_out(const u16* __restrict__ yb,
                                                  const u16* __restrict__ wb,
                                                  const float* __restrict__ bias,
                                                  float* __restrict__ out){
    __shared__ u16 As[2][BM*BK];
    __shared__ u16 Bs[2][BN*BK];
    int bx = (blockIdx.x & 7)*98 + (blockIdx.x >> 3);    // XCD-chunked
    int mt = bx >> 2, nt = bx & 3;
    int pix0 = mt*BM, o0 = nt*BN;
    int t = threadIdx.x;
    int wid = t >> 6, lane = t & 63;
    int wm = wid >> 1, wn = wid & 1;
    int l15 = lane & 15, hi = lane >> 4;
    f32x4 acc[4][4];
    #pragma unroll
    for (int i = 0; i < 4; i++)
        #pragma unroll
        for (int j = 0; j < 4; j++) acc[i][j] = (f32x4){0.f,0.f,0.f,0.f};

    auto STAGE = [&](int sel, int ks){
        int K0 = ks*BK;
        #pragma unroll
        for (int i = 0; i < 4; i++){
            int off = t*16 + i*4096;
            int row = off >> 7;
            int cs  = ((off & 127) >> 1) ^ sw8(row);
            gld16(yb + (size_t)(pix0+row)*CCH + K0 + cs, (char*)As[sel] + off);
            gld16(wb + (size_t)(o0 +row)*CCH + K0 + cs, (char*)Bs[sel] + off);
        }
    };
    STAGE(0, 0);
    asm volatile("s_waitcnt vmcnt(0)" ::: "memory");
    asm volatile("s_barrier" ::: "memory");
    for (int ks = 0; ks < CCH/BK; ks++){
        int cur = ks & 1;
        if (ks < CCH/BK - 1) STAGE(cur ^ 1, ks + 1);
        const u16* Ac = As[cur];
        const u16* Bc = Bs[cur];
        #pragma unroll
        for (int kk = 0; kk < 2; kk++){
            u16x8 af[4], bf[4];
            #pragma unroll
            for (int i = 0; i < 4; i++){
                int rowA = wm*64 + i*16 + l15;
                af[i] = *(const u16x8*)&Ac[rowA*BK + ((kk*32 + hi*8) ^ sw8(rowA))];
            }
            #pragma unroll
            for (int j = 0; j < 4; j++){
                int rowB = wn*64 + j*16 + l15;
                bf[j] = *(const u16x8*)&Bc[rowB*BK + ((kk*32 + hi*8) ^ sw8(rowB))];
            }
            #pragma unroll
            for (int i = 0; i < 4; i++)
                #pragma unroll
                for (int j = 0; j < 4; j++)
                    acc[i][j] = MFMA(af[i], bf[j], acc[i][j]);
        }
        asm volatile("s_waitcnt vmcnt(0)" ::: "memory");
        asm volatile("s_barrier" ::: "memory");
    }
    #pragma unroll
    for (int i = 0; i < 4; i++){
        #pragma unroll
        for (int j = 0; j < 4; j++){
            int o = o0 + wn*64 + j*16 + l15;
            float bv = bias[o];
            #pragma unroll
            for (int r = 0; r < 4; r++){
                int pix = pix0 + wm*64 + i*16 + 4*hi + r;
                out[(size_t)pix*CCH + o] = acc[i][j][r] + bv;
            }
        }
    }
}

// ---------------- launch ----------------
extern "C" void kernel_launch(void* const* d_in, const int* in_sizes, int n_in,
                              void* d_out, int out_size, void* d_ws, size_t ws_size,
                              hipStream_t stream){
    const float* x      = (const float*)d_in[0];
    const float* qkv_w  = (const float*)d_in[1];
    const float* qkv_b  = (const float*)d_in[2];
    const float* lepe_w = (const float*)d_in[3];
    const float* lepe_b = (const float*)d_in[4];
    const float* out_w  = (const float*)d_in[5];
    const float* out_b  = (const float*)d_in[6];

    char* w = (char*)d_ws;
    u16*   xb   = (u16*)(w + 0);
    u16*   wqkv = (u16*)(w + 25690112);
    u16*   wout = (u16*)(w + 27262976);
    u16*   q_s  = (u16*)(w + 27787264);
    u16*   k_s  = (u16*)(w + 53477376);
    u16*   v_s  = (u16*)(w + 79167488);
    float* xp   = (float*)(w + 104857600);
    float* qkp  = (float*)(w + 105660416);
    int*   idx  = (int*)(w + 107266048);
    u16*   yb   = (u16*)(w + 107272320);
    float* xpp  = (float*)(w + 132962432);
    float* qkpp = (float*)(w + 139384960);

    k_pool1<<<dim3(BB*NREG*8), dim3(256), 0, stream>>>(x, xb, xpp);
    k_pool2<<<dim3(BB*NREG*2), dim3(256), 0, stream>>>(xpp, xp);
    k_conv_w<<<dim3(512), dim3(256), 0, stream>>>(qkv_w, wqkv, out_w, wout);
    k_qk_pool<<<dim3(448), dim3(256), 0, stream>>>(xp, qkv_w, qkpp);
    k_qkp_red<<<dim3(BB*NREG*4), dim3(256), 0, stream>>>(qkpp, qkv_b, qkp);
    k_route<<<dim3(BB*NREG), dim3(64), 0, stream>>>(qkp, idx);
    k_gemm_qkv<<<dim3((NPIX/BM)*(OC/BN)), dim3(256), 0, stream>>>(xb, wqkv, qkv_b, q_s, k_s, v_s);
    k_attn<<<dim3(BB*NHEADS*NREG), dim3(256), 0, stream>>>(q_s, k_s, v_s, idx, lepe_w, lepe_b, yb);
    k_gemm_out<<<dim3((NPIX/BM)*(CCH/BN)), dim3(256), 0, stream>>>(yb, wout, out_b, (float*)d_out);
}

// Round 14
// 172.469 us; speedup vs baseline: 1.1214x; 1.0952x over previous
//
#include <hip/hip_runtime.h>
#include <stdint.h>

#define BB      8
#define HH      56
#define WWD     56
#define CCH     512
#define NHEADS  8
#define HD      64
#define NWIN    7
#define NREG    49
#define RSZ     64
#define TOPKK   4
#define PPI     (HH*WWD)        // 3136
#define NPIX    (BB*PPI)        // 25088
#define OC      (3*CCH)         // 1536
#define SCALE_F 0.04419417382415922f

typedef unsigned short u16;
typedef u16   u16x8 __attribute__((ext_vector_type(8)));
typedef u16   u16x4 __attribute__((ext_vector_type(4)));
typedef __bf16 b16x8 __attribute__((ext_vector_type(8)));
typedef float f32x4 __attribute__((ext_vector_type(4)));
typedef int   i32x4 __attribute__((ext_vector_type(4)));

__device__ __forceinline__ u16 f2b(float f){
    return __builtin_bit_cast(unsigned short, (__bf16)f);   // v_cvt_pk_bf16_f32, RNE
}
__device__ __forceinline__ float b2f(u16 h){
    return __builtin_bit_cast(float, (unsigned)h << 16);
}
__device__ __forceinline__ f32x4 MFMA(u16x8 a, u16x8 b, f32x4 c){
    return __builtin_amdgcn_mfma_f32_16x16x32_bf16(
        __builtin_bit_cast(b16x8, a), __builtin_bit_cast(b16x8, b), c, 0, 0, 0);
}
// XOR-swizzle term (u16-index units, 16B granular)
__device__ __forceinline__ int sw8(int row){ return ((row ^ (row >> 3)) & 7) << 3; }

// async global->LDS 16B
__device__ __forceinline__ void gld16(const void* g, void* l){
    auto gp = (const __attribute__((address_space(1))) unsigned int*)(unsigned long long)(g);
    auto lp = (__attribute__((address_space(3))) unsigned int*)(unsigned int)(unsigned long long)(l);
    __builtin_amdgcn_global_load_lds(gp, lp, 16, 0, 0);
}

// ---------------- fused: x fp32->bf16 convert + per-(region,row) channel sums ----------------
__global__ __launch_bounds__(256) void k_pool1(const float* __restrict__ x,
                                               u16* __restrict__ xb,
                                               float* __restrict__ xpp){
    __shared__ f32x4 ps[128];
    int blk = blockIdx.x;
    int br = blk >> 3, a = blk & 7;
    int b = br / NREG, reg = br % NREG;
    int rh = reg / NWIN, rw = reg % NWIN;
    size_t base_off = ((size_t)b*PPI + (rh*8 + a)*WWD + rw*8) * CCH;
    const f32x4* src = (const f32x4*)(x + base_off);
    u16* xbase = xb + base_off;
    int t = threadIdx.x;
    f32x4 s4 = (f32x4){0.f,0.f,0.f,0.f};
    #pragma unroll
    for (int i = 0; i < 4; i++){
        int c4 = t + 256*i;
        f32x4 v = src[c4];
        s4 += v;
        u16x4 o4; o4[0]=f2b(v[0]); o4[1]=f2b(v[1]); o4[2]=f2b(v[2]); o4[3]=f2b(v[3]);
        *(u16x4*)(xbase + c4*4) = o4;
    }
    if (t >= 128) ps[t-128] = s4;
    __syncthreads();
    if (t < 128){
        f32x4 r = ps[t];
        r += s4;
        *(f32x4*)(xpp + (size_t)blk*CCH + t*4) = r;
    }
}

// ---------------- pool stage 2: sum the 8 row-partials, /64. grid 784 ----------------
__global__ __launch_bounds__(256) void k_pool2(const float* __restrict__ xpp,
                                               float* __restrict__ xp){
    int i = blockIdx.x*256 + threadIdx.x;
    int br = i >> 9, c = i & 511;
    float s = 0.f;
    #pragma unroll
    for (int a = 0; a < 8; a++) s += xpp[((size_t)(br*8 + a))*CCH + c];
    xp[i] = s * (1.0f/64.0f);
}

// ---------------- both weight converts in one launch ----------------
__global__ __launch_bounds__(256) void k_conv_w(const float* __restrict__ w1,
                                                u16* __restrict__ d1,
                                                const float* __restrict__ w2,
                                                u16* __restrict__ d2){
    int i = blockIdx.x * 256 + threadIdx.x;
    const float* src = w1; u16* dst = d1;
    if (i >= OC*CCH/8){ i -= OC*CCH/8; src = w2; dst = d2; }
    const f32x4* s = (const f32x4*)src;
    f32x4 a = s[2*i], b = s[2*i+1];
    u16x8 o;
    o[0]=f2b(a[0]); o[1]=f2b(a[1]); o[2]=f2b(a[2]); o[3]=f2b(a[3]);
    o[4]=f2b(b[0]); o[5]=f2b(b[1]); o[6]=f2b(b[2]); o[7]=f2b(b[3]);
    *(u16x8*)(dst + 8*i) = o;
}

// ---------------- pooled q/k projection: fp32 split-K GEMM -> partials ----------------
#define QP_BM 64
#define QP_BN 64
#define QP_BK 32
#define QP_KS 4
__global__ __launch_bounds__(256) void k_qk_pool(const float* __restrict__ xp,
                                                 const float* __restrict__ qkv_w,
                                                 float* __restrict__ qkpp){
    __shared__ float Xs[QP_BK][QP_BM+4];
    __shared__ float Ws[QP_BK][QP_BN+4];
    int bx = blockIdx.x;                 // 7 mt x 16 nt x 4 kt = 448
    int kt = bx & 3, nt = (bx >> 2) & 15, mt = bx >> 6;
    int row0 = mt*QP_BM, o0 = nt*QP_BN, kbase = kt*(CCH/QP_KS);
    int t = threadIdx.x;
    int tx = t & 15, ty = t >> 4;
    float acc[4][4];
    #pragma unroll
    for (int i = 0; i < 4; i++)
        #pragma unroll
        for (int j = 0; j < 4; j++) acc[i][j] = 0.f;

    for (int ks = 0; ks < (CCH/QP_KS)/QP_BK; ks++){
        int k0 = kbase + ks*QP_BK;
        #pragma unroll
        for (int i = 0; i < 8; i++){
            int idx = t + 256*i;
            int row = idx >> 5, col = idx & 31;
            int gr = row0 + row;
            Xs[col][row] = (gr < BB*NREG) ? xp[(size_t)gr*CCH + k0 + col] : 0.f;
            Ws[col][row] = qkv_w[(size_t)(o0 + row)*CCH + k0 + col];
        }
        __syncthreads();
        #pragma unroll
        for (int kk = 0; kk < QP_BK; kk++){
            f32x4 a4 = *(const f32x4*)&Xs[kk][ty*4];
            f32x4 b4 = *(const f32x4*)&Ws[kk][tx*4];
            #pragma unroll
            for (int i = 0; i < 4; i++)
                #pragma unroll
                for (int j = 0; j < 4; j++)
                    acc[i][j] += a4[i] * b4[j];
        }
        __syncthreads();
    }
    float* dst = qkpp + (size_t)kt*(BB*NREG*1024);
    #pragma unroll
    for (int i = 0; i < 4; i++){
        int r = row0 + ty*4 + i;
        if (r >= BB*NREG) continue;
        #pragma unroll
        for (int j = 0; j < 4; j++){
            int o = o0 + tx*4 + j;
            dst[(size_t)r*1024 + o] = acc[i][j];
        }
    }
}

// ---------------- reduce split-K partials + bias. grid 1568 ----------------
__global__ __launch_bounds__(256) void k_qkp_red(const float* __restrict__ qkpp,
                                                 const float* __restrict__ qkv_b,
                                                 float* __restrict__ qkp){
    int i = blockIdx.x*256 + threadIdx.x;
    int o = i & 1023;
    float s = qkv_b[o];
    #pragma unroll
    for (int kt = 0; kt < QP_KS; kt++)
        s += qkpp[(size_t)kt*(BB*NREG*1024) + i];
    qkp[i] = s;
}

// ---------------- a_r scores + top-4: 4 waves stride regions, bit-identical scores ----------------
__global__ __launch_bounds__(256) void k_route(const float* __restrict__ qkp,
                                               int* __restrict__ idx){
    int blk = blockIdx.x;
    int b = blk / NREG;
    int t = threadIdx.x, wv = t >> 6, lane = t & 63;
    __shared__ float sc[NREG];
    const float* qr = qkp + (size_t)blk*1024;
    float qv[8];
    #pragma unroll
    for (int i = 0; i < 8; i++) qv[i] = qr[lane + 64*i];
    for (int j = wv; j < NREG; j += 4){
        const float* kr = qkp + ((size_t)(b*NREG + j)*1024 + 512);
        float p = 0.f;
        #pragma unroll
        for (int i = 0; i < 8; i++) p += qv[i] * kr[lane + 64*i];
        #pragma unroll
        for (int msk = 32; msk >= 1; msk >>= 1) p += __shfl_xor(p, msk, 64);
        if (lane == 0) sc[j] = p;
    }
    __syncthreads();
    if (t == 0){
        #pragma unroll
        for (int tt = 0; tt < TOPKK; tt++){
            float best = -1e30f; int bj = 0;
            for (int j = 0; j < NREG; j++){
                if (sc[j] > best){ best = sc[j]; bj = j; }
            }
            idx[blk*TOPKK + tt] = bj;
            sc[bj] = -1e30f;
        }
    }
}

// ---------------- QKV GEMM: r11-proven 4-wave dbuf, single raw barrier per K-step ----------------
#define BM 128
#define BN 128
#define BK 64
__global__ __launch_bounds__(256) void k_gemm_qkv(const u16* __restrict__ xb,
                                                  const u16* __restrict__ wb,
                                                  const float* __restrict__ bias,
                                                  u16* __restrict__ q_s,
                                                  u16* __restrict__ k_s,
                                                  u16* __restrict__ v_s){
    __shared__ u16 As[2][BM*BK];
    __shared__ u16 Bs[2][BN*BK];
    int bx = (blockIdx.x & 7)*294 + (blockIdx.x >> 3);   // XCD-chunked
    int mt = bx / (OC/BN), nt = bx % (OC/BN);
    int pix0 = mt*BM, o0 = nt*BN;
    int t = threadIdx.x;
    int wid = t >> 6, lane = t & 63;
    int wm = wid >> 1, wn = wid & 1;
    int l15 = lane & 15, hi = lane >> 4;
    f32x4 acc[4][4];
    #pragma unroll
    for (int i = 0; i < 4; i++)
        #pragma unroll
        for (int j = 0; j < 4; j++) acc[i][j] = (f32x4){0.f,0.f,0.f,0.f};

    auto STAGE = [&](int sel, int ks){
        int K0 = ks*BK;
        #pragma unroll
        for (int i = 0; i < 4; i++){
            int off = t*16 + i*4096;
            int row = off >> 7;
            int cs  = ((off & 127) >> 1) ^ sw8(row);
            gld16(xb + (size_t)(pix0+row)*CCH + K0 + cs, (char*)As[sel] + off);
            gld16(wb + (size_t)(o0 +row)*CCH + K0 + cs, (char*)Bs[sel] + off);
        }
    };
    STAGE(0, 0);
    asm volatile("s_waitcnt vmcnt(0)" ::: "memory");
    asm volatile("s_barrier" ::: "memory");
    for (int ks = 0; ks < CCH/BK; ks++){
        int cur = ks & 1;
        if (ks < CCH/BK - 1) STAGE(cur ^ 1, ks + 1);
        const u16* Ac = As[cur];
        const u16* Bc = Bs[cur];
        #pragma unroll
        for (int kk = 0; kk < 2; kk++){
            u16x8 af[4], bf[4];
            #pragma unroll
            for (int i = 0; i < 4; i++){
                int rowA = wm*64 + i*16 + l15;
                af[i] = *(const u16x8*)&Ac[rowA*BK + ((kk*32 + hi*8) ^ sw8(rowA))];
            }
            #pragma unroll
            for (int j = 0; j < 4; j++){
                int rowB = wn*64 + j*16 + l15;
                bf[j] = *(const u16x8*)&Bc[rowB*BK + ((kk*32 + hi*8) ^ sw8(rowB))];
            }
            #pragma unroll
            for (int i = 0; i < 4; i++)
                #pragma unroll
                for (int j = 0; j < 4; j++)
                    acc[i][j] = MFMA(af[i], bf[j], acc[i][j]);
        }
        asm volatile("s_waitcnt vmcnt(0)" ::: "memory");
        asm volatile("s_barrier" ::: "memory");
    }
    #pragma unroll
    for (int i = 0; i < 4; i++){
        int pix = pix0 + wm*64 + i*16 + 4*hi;
        int b  = pix / PPI;
        int pp = pix - b*PPI;
        int h  = pp / WWD, w2 = pp - h*WWD;
        int reg = (h >> 3)*NWIN + (w2 >> 3);
        int pr  = (h & 7)*8 + (w2 & 7);
        size_t base0 = ((size_t)(b*NHEADS)*NREG + reg)*RSZ + pr;
        #pragma unroll
        for (int j = 0; j < 4; j++){
            int o = o0 + wn*64 + j*16 + l15;
            int which = o >> 9;
            int c = o & 511;
            int m = c >> 6, d = c & 63;
            float bv = bias[o];
            u16* dst = (which == 0) ? q_s : (which == 1) ? k_s : v_s;
            size_t oi = (base0 + (size_t)m*(NREG*RSZ))*HD + d;
            #pragma unroll
            for (int r = 0; r < 4; r++)
                dst[oi + (size_t)r*HD] = f2b(acc[i][j][r] + bv);
        }
    }
}

// ---------------- fused attention + LEPE: 40KB LDS, 3 blocks/CU, pipelined PV + setprio ----------------
__global__ __launch_bounds__(256, 3) void k_attn(const u16* __restrict__ q_s,
                                              const u16* __restrict__ k_s,
                                              const u16* __restrict__ v_s,
                                              const int* __restrict__ idx,
                                              const float* __restrict__ lw,
                                              const float* __restrict__ lb,
                                              u16* __restrict__ yb){
    __shared__ __align__(16) char smem[32768 + 8192];
    u16*   Ks = (u16*)smem;
    u16*   Vt = (u16*)(smem + 32768);
    float* Wl = (float*)(smem + 14400);          // inside Ks region, after 100*72 u16 halo
    float* Bl = (float*)(smem + 14400 + 2304);
    int bid = (blockIdx.x & 7)*392 + (blockIdx.x >> 3);  // XCD-chunked
    int b  = bid / (NHEADS*NREG);
    int r2 = bid % (NHEADS*NREG);
    int m = r2 / NREG, qreg = r2 % NREG;
    int rh = qreg / NWIN, rw = qreg % NWIN;
    int t = threadIdx.x, wid = t >> 6, lane = t & 63;
    int l15 = lane & 15, hi = lane >> 4;

    size_t hb = (size_t)(b*NHEADS + m)*NREG;
    int i4[4];
    #pragma unroll
    for (int j = 0; j < 4; j++) i4[j] = idx[(b*NREG + qreg)*TOPKK + j];

    // lepe halo loads early (10x10 cells x 64 d, 8 d per chunk -> 800 chunks)
    u16x8 halo0 = (u16x8){0,0,0,0,0,0,0,0}, halo1 = halo0, halo2 = halo0, halo3 = halo0;
    #pragma unroll
    for (int i = 0; i < 4; i++){
        int c = t + 256*i;
        if (c < 800){
            int cell = c >> 3, part = c & 7;
            int hr = cell / 10, wc = cell % 10;
            int hh2 = rh*8 - 1 + hr, ww2 = rw*8 - 1 + wc;
            if (hh2 >= 0 && hh2 < HH && ww2 >= 0 && ww2 < WWD){
                int reg2 = (hh2 >> 3)*NWIN + (ww2 >> 3);
                int pr2  = (hh2 & 7)*8 + (ww2 & 7);
                u16x8 v8 = *(const u16x8*)&v_s[((hb + reg2)*RSZ + pr2)*HD + part*8];
                if (i == 0) halo0 = v8; else if (i == 1) halo1 = v8;
                else if (i == 2) halo2 = v8; else halo3 = v8;
            }
        }
    }

    // stage K via global_load_lds (swizzled through source column)
    #pragma unroll
    for (int i = 0; i < 8; i++){
        int off = t*16 + i*4096;
        int rsel = off >> 13;
        int row  = off >> 7;
        int cs   = ((off & 127) >> 1) ^ sw8(row);
        gld16(k_s + (hb + i4[rsel])*(RSZ*HD) + (size_t)(row & 63)*HD + cs,
              (char*)Ks + off);
    }
    const u16* qb = q_s + (hb + qreg)*(RSZ*HD);
    u16x8 aq[2];
    #pragma unroll
    for (int kk = 0; kk < 2; kk++)
        aq[kk] = *(const u16x8*)&qb[(wid*16 + l15)*HD + kk*32 + hi*8];
    __syncthreads();

    // QK^T (setprio around MFMA cluster: T5)
    f32x4 s[16];
    #pragma unroll
    for (int fn = 0; fn < 16; fn++) s[fn] = (f32x4){0.f,0.f,0.f,0.f};
    __builtin_amdgcn_s_setprio(1);
    #pragma unroll
    for (int kk = 0; kk < 2; kk++)
        #pragma unroll
        for (int fn = 0; fn < 16; fn++){
            int rowK = fn*16 + l15;
            u16x8 bf = *(const u16x8*)&Ks[rowK*HD + ((kk*32 + hi*8) ^ sw8(rowK))];
            s[fn] = MFMA(aq[kk], bf, s[fn]);
        }
    __builtin_amdgcn_s_setprio(0);
    // softmax: no max-sub (|s*scale| <= ~60 << 88 fp32-exp limit); inv deferred to post-PV
    const float K2 = SCALE_F * 1.4426950408889634f;  // scale * log2(e)
    float inv[4];
    #pragma unroll
    for (int rr = 0; rr < 4; rr++){
        float ss = 0.f;
        #pragma unroll
        for (int fn = 0; fn < 16; fn++){
            float e = exp2f(s[fn][rr] * K2);
            s[fn][rr] = e; ss += e;
        }
        #pragma unroll
        for (int msk = 1; msk < 16; msk <<= 1) ss += __shfl_xor(ss, msk, 64);
        inv[rr] = 1.0f / ss;
    }
    __syncthreads();
    // write unnormalized P (bf16) into Ks region as swizzled [64][256]
    #pragma unroll
    for (int fn = 0; fn < 16; fn++)
        #pragma unroll
        for (int rr = 0; rr < 4; rr++){
            int rowP = wid*16 + 4*hi + rr;
            Ks[rowP*256 + ((fn*16 + l15) ^ sw8(rowP))] = f2b(s[fn][rr]);
        }
    __syncthreads();

    // preload all 8 P fragments, then Ks region is free
    int rowP = wid*16 + l15;
    u16x8 pa8[8];
    #pragma unroll
    for (int ksx = 0; ksx < 8; ksx++)
        pa8[ksx] = *(const u16x8*)&Ks[rowP*256 + ((ksx*32 + hi*8) ^ sw8(rowP))];
    __syncthreads();               // all waves done reading P -> Ks reusable

    // issue PV phase-0 global loads NOW (consumed in first scatter; overlap halo/Wl staging)
    int keyA = t >> 1,        dhA = t & 1;          // c2 = t
    int keyB = (t+256) >> 1,  dhB = (t+256) & 1;    // c2 = t+256
    const u16* vbaseA = v_s + (hb + i4[keyA >> 6])*(RSZ*HD) + (size_t)(keyA & 63)*HD;
    const u16* vbaseB = v_s + (hb + i4[keyB >> 6])*(RSZ*HD) + (size_t)(keyB & 63)*HD;
    u16x8 ga = *(const u16x8*)&vbaseA[0*16 + dhA*8];
    u16x8 gb = *(const u16x8*)&vbaseB[0*16 + dhB*8];

    // halo + lepe weights -> Ks region
    #pragma unroll
    for (int i = 0; i < 4; i++){
        int c = t + 256*i;
        if (c < 800){
            int cell = c >> 3, part = c & 7;
            u16x8 v8 = (i == 0) ? halo0 : (i == 1) ? halo1 : (i == 2) ? halo2 : halo3;
            *(u16x8*)&Ks[cell*72 + part*8] = v8;
        }
    }
    #pragma unroll
    for (int i2 = t; i2 < 640; i2 += 256){
        if (i2 < 576) Wl[i2] = lw[m*576 + i2];
        else Bl[i2-576] = lb[m*64 + (i2-576)];
    }

    // PV: 4 phases; phase j+1's global loads issue before phase j's MFMA (latency hidden)
    f32x4 o[4];
    #pragma unroll
    for (int j = 0; j < 4; j++) o[j] = (f32x4){0.f,0.f,0.f,0.f};
    #pragma unroll
    for (int j = 0; j < 4; j++){
        // scatter current phase's registers into Vt (swizzled transpose)
        #pragma unroll
        for (int jj = 0; jj < 8; jj++){
            int rowA = dhA*8 + jj;
            Vt[rowA*256 + (keyA ^ sw8(rowA))] = ga[jj];
            int rowB = dhB*8 + jj;
            Vt[rowB*256 + (keyB ^ sw8(rowB))] = gb[jj];
        }
        __syncthreads();                           // Vt writes visible
        u16x8 na, nb;
        if (j < 3){                                // issue next phase's loads early
            na = *(const u16x8*)&vbaseA[(j+1)*16 + dhA*8];
            nb = *(const u16x8*)&vbaseB[(j+1)*16 + dhB*8];
        }
        __builtin_amdgcn_s_setprio(1);
        #pragma unroll
        for (int ksx = 0; ksx < 8; ksx++){
            u16x8 vb = *(const u16x8*)&Vt[l15*256 + ((ksx*32 + hi*8) ^ sw8(l15))];
            o[j] = MFMA(pa8[ksx], vb, o[j]);
        }
        __builtin_amdgcn_s_setprio(0);
        __syncthreads();                           // PV reads done before next scatter
        if (j < 3){ ga = na; gb = nb; }
    }
    // deferred softmax normalization (lane-local: o row = 4*hi+rr matches inv[rr])
    #pragma unroll
    for (int j = 0; j < 4; j++)
        #pragma unroll
        for (int rr = 0; rr < 4; rr++) o[j][rr] *= inv[rr];

    // lepe + output, 6-col register window
    int a_row = wid*2 + (hi >> 1);
    int col0  = (hi & 1)*4;
    #pragma unroll
    for (int j = 0; j < 4; j++){
        int d = j*16 + l15;
        float w9[9];
        #pragma unroll
        for (int tap = 0; tap < 9; tap++) w9[tap] = Wl[d*9 + tap];
        float bias = Bl[d];
        float accL[4] = {bias, bias, bias, bias};
        #pragma unroll
        for (int kh = 0; kh < 3; kh++){
            float c6[6];
            #pragma unroll
            for (int ii = 0; ii < 6; ii++)
                c6[ii] = b2f(Ks[((a_row + kh)*10 + col0 + ii)*72 + d]);
            #pragma unroll
            for (int rr = 0; rr < 4; rr++)
                #pragma unroll
                for (int kw = 0; kw < 3; kw++)
                    accL[rr] += c6[rr + kw] * w9[kh*3 + kw];
        }
        #pragma unroll
        for (int rr = 0; rr < 4; rr++){
            float val = o[j][rr] + accL[rr];
            int col = col0 + rr;
            int h = rh*8 + a_row, w2c = rw*8 + col;
            yb[((size_t)b*PPI + h*WWD + w2c)*CCH + m*HD + d] = f2b(val);
        }
    }
}

// ---------------- output GEMM: r11-proven 4-wave dbuf, single raw barrier per K-step ----------------
__global__ __launch_bounds__(256) void k_gemm_out(const u16* __restrict__ yb,
                                                  const u16* __restrict__ wb,
                                                  const float* __restrict__ bias,
                                                  float* __restrict__ out){
    __shared__ u16 As[2][BM*BK];
    __shared__ u16 Bs[2][BN*BK];
    int bx = (blockIdx.x & 7)*98 + (blockIdx.x >> 3);    // XCD-chunked
    int mt = bx >> 2, nt = bx & 3;
    int pix0 = mt*BM, o0 = nt*BN;
    int t = threadIdx.x;
    int wid = t >> 6, lane = t & 63;
    int wm = wid >> 1, wn = wid & 1;
    int l15 = lane & 15, hi = lane >> 4;
    f32x4 acc[4][4];
    #pragma unroll
    for (int i = 0; i < 4; i++)
        #pragma unroll
        for (int j = 0; j < 4; j++) acc[i][j] = (f32x4){0.f,0.f,0.f,0.f};

    auto STAGE = [&](int sel, int ks){
        int K0 = ks*BK;
        #pragma unroll
        for (int i = 0; i < 4; i++){
            int off = t*16 + i*4096;
            int row = off >> 7;
            int cs  = ((off & 127) >> 1) ^ sw8(row);
            gld16(yb + (size_t)(pix0+row)*CCH + K0 + cs, (char*)As[sel] + off);
            gld16(wb + (size_t)(o0 +row)*CCH + K0 + cs, (char*)Bs[sel] + off);
        }
    };
    STAGE(0, 0);
    asm volatile("s_waitcnt vmcnt(0)" ::: "memory");
    asm volatile("s_barrier" ::: "memory");
    for (int ks = 0; ks < CCH/BK; ks++){
        int cur = ks & 1;
        if (ks < CCH/BK - 1) STAGE(cur ^ 1, ks + 1);
        const u16* Ac = As[cur];
        const u16* Bc = Bs[cur];
        #pragma unroll
        for (int kk = 0; kk < 2; kk++){
            u16x8 af[4], bf[4];
            #pragma unroll
            for (int i = 0; i < 4; i++){
                int rowA = wm*64 + i*16 + l15;
                af[i] = *(const u16x8*)&Ac[rowA*BK + ((kk*32 + hi*8) ^ sw8(rowA))];
            }
            #pragma unroll
            for (int j = 0; j < 4; j++){
                int rowB = wn*64 + j*16 + l15;
                bf[j] = *(const u16x8*)&Bc[rowB*BK + ((kk*32 + hi*8) ^ sw8(rowB))];
            }
            #pragma unroll
            for (int i = 0; i < 4; i++)
                #pragma unroll
                for (int j = 0; j < 4; j++)
                    acc[i][j] = MFMA(af[i], bf[j], acc[i][j]);
        }
        asm volatile("s_waitcnt vmcnt(0)" ::: "memory");
        asm volatile("s_barrier" ::: "memory");
    }
    #pragma unroll
    for (int i = 0; i < 4; i++){
        #pragma unroll
        for (int j = 0; j < 4; j++){
            int o = o0 + wn*64 + j*16 + l15;
            float bv = bias[o];
            #pragma unroll
            for (int r = 0; r < 4; r++){
                int pix = pix0 + wm*64 + i*16 + 4*hi + r;
                out[(size_t)pix*CCH + o] = acc[i][j][r] + bv;
            }
        }
    }
}

// ---------------- launch ----------------
extern "C" void kernel_launch(void* const* d_in, const int* in_sizes, int n_in,
                              void* d_out, int out_size, void* d_ws, size_t ws_size,
                              hipStream_t stream){
    const float* x      = (const float*)d_in[0];
    const float* qkv_w  = (const float*)d_in[1];
    const float* qkv_b  = (const float*)d_in[2];
    const float* lepe_w = (const float*)d_in[3];
    const float* lepe_b = (const float*)d_in[4];
    const float* out_w  = (const float*)d_in[5];
    const float* out_b  = (const float*)d_in[6];

    char* w = (char*)d_ws;
    u16*   xb   = (u16*)(w + 0);
    u16*   wqkv = (u16*)(w + 25690112);
    u16*   wout = (u16*)(w + 27262976);
    u16*   q_s  = (u16*)(w + 27787264);
    u16*   k_s  = (u16*)(w + 53477376);
    u16*   v_s  = (u16*)(w + 79167488);
    float* xp   = (float*)(w + 104857600);
    float* qkp  = (float*)(w + 105660416);
    int*   idx  = (int*)(w + 107266048);
    u16*   yb   = (u16*)(w + 107272320);
    float* xpp  = (float*)(w + 132962432);
    float* qkpp = (float*)(w + 139384960);

    k_pool1<<<dim3(BB*NREG*8), dim3(256), 0, stream>>>(x, xb, xpp);
    k_pool2<<<dim3(BB*NREG*2), dim3(256), 0, stream>>>(xpp, xp);
    k_conv_w<<<dim3(512), dim3(256), 0, stream>>>(qkv_w, wqkv, out_w, wout);
    k_qk_pool<<<dim3(448), dim3(256), 0, stream>>>(xp, qkv_w, qkpp);
    k_qkp_red<<<dim3(BB*NREG*4), dim3(256), 0, stream>>>(qkpp, qkv_b, qkp);
    k_route<<<dim3(BB*NREG), dim3(256), 0, stream>>>(qkp, idx);
    k_gemm_qkv<<<dim3((NPIX/BM)*(OC/BN)), dim3(256), 0, stream>>>(xb, wqkv, qkv_b, q_s, k_s, v_s);
    k_attn<<<dim3(BB*NHEADS*NREG), dim3(256), 0, stream>>>(q_s, k_s, v_s, idx, lepe_w, lepe_b, yb);
    k_gemm_out<<<dim3((NPIX/BM)*(CCH/BN)), dim3(256), 0, stream>>>(yb, wout, out_b, (float*)d_out);
}